// Round 4
// baseline (67.368 us; speedup 1.0000x reference)
//
#include <hip/hip_runtime.h>

// Chamfer-style 3-level loss. P=128, N=128 pred pts, M=1024 gt pts.
// R3 evidence: measured window = 40us harness ws-poison fill (HBM roofline,
// fixed) + ~20us graph-node overhead (fixed) + ~5us our kernels. R4 change:
// packed dual-fp32 math (v_pk_fma_f32 etc. via <2 x float> IR) to cut K1's
// VALU instr count 1280 -> ~800 per thread; K2 shrunk to a single wave.
#define NPOLY 128
#define NPTS  128
#define NGT   1024
#define NBLK  (3 * NPOLY * 2)   // 768 partials

typedef float v2f __attribute__((ext_vector_type(2)));

__global__ __launch_bounds__(256) void chamfer_partial_kernel(
    const float* __restrict__ pred0,
    const float* __restrict__ pred1,
    const float* __restrict__ pred2,
    const float* __restrict__ gt,
    float* __restrict__ partial) {
    __shared__ float4 gts[NGT / 2];   // 8 KiB: this polygon's gt point-pairs
    __shared__ float2 pxy[64];        // this block's 64 pred points
    __shared__ float wave_sums[4];

    const int b     = blockIdx.x;
    const int half  = b & 1;
    const int poly  = (b >> 1) & (NPOLY - 1);
    const int level = b >> 8;         // 256 blocks per level

    const float* pred = (level == 0) ? pred0 : ((level == 1) ? pred1 : pred2);
    const float  w    = (level == 0) ? 0.2f : ((level == 1) ? 0.3f : 0.5f);

    const int t = threadIdx.x;

    // Stage gt: 512 float4 (coalesced, 2 per thread).
    const float4* gsrc = (const float4*)(gt + (size_t)poly * (NGT * 2));
    gts[t]       = gsrc[t];
    gts[t + 256] = gsrc[t + 256];

    // Stage this block's 64 pred points: coords [1:3] of [P,N,3] layout.
    if (t < 64) {
        const float* pp = pred + ((size_t)poly * NPTS + half * 64 + t) * 3 + 1;
        pxy[t] = make_float2(pp[0], pp[1]);
    }
    __syncthreads();

    const int s = t & 31;    // gt slice
    const int g = t >> 5;    // point-group 0..7

    v2f pxv[8], pyv[8];
    float dmin[8];
#pragma unroll
    for (int p = 0; p < 8; ++p) {
        float2 q = pxy[g * 8 + p];   // 32-lane broadcast, conflict-free
        pxv[p] = (v2f){q.x, q.x};
        pyv[p] = (v2f){q.y, q.y};
        dmin[p] = 1e30f;
    }

    // Each wave scans the full gt set: 16 ds_read_b128/thread. Packed math:
    // per 2 distances: 2x pk_sub + pk_mul + pk_fma + 2x scalar min = 6 VALU
    // (was 10 scalar).
#pragma unroll
    for (int j = 0; j < NGT / 2 / 32; ++j) {
        float4 gq = gts[(j << 5) + s];
        v2f gx = (v2f){gq.x, gq.z};
        v2f gy = (v2f){gq.y, gq.w};
#pragma unroll
        for (int p = 0; p < 8; ++p) {
            v2f dx = pxv[p] - gx;
            v2f dy = pyv[p] - gy;
            v2f d2 = dx * dx + dy * dy;   // pk_mul + pk_fma
            dmin[p] = fminf(dmin[p], fminf(d2.x, d2.y));
        }
    }

    // Min across the 32 slices.
#pragma unroll
    for (int o = 1; o <= 16; o <<= 1) {
#pragma unroll
        for (int p = 0; p < 8; ++p)
            dmin[p] = fminf(dmin[p], __shfl_xor(dmin[p], o));
    }

    // sqrt AFTER the full min (monotone -> same selection as reference).
    float d = 0.0f;
#pragma unroll
    for (int p = 0; p < 8; ++p) d += sqrtf(dmin[p]);

    // Other point-group in this wave -> wave total (16 points).
    d += __shfl_xor(d, 32);

    if ((t & 63) == 0) wave_sums[t >> 6] = d;
    __syncthreads();

    if (t == 0) {
        float total = wave_sums[0] + wave_sums[1] + wave_sums[2] + wave_sums[3];
        partial[b] = total * (w * (1.0f / (3.0f * NPOLY * NPTS)));
    }
}

// Single wave: sum 768 partials (L2-resident), plain scalar store.
__global__ __launch_bounds__(64) void reduce_partials_kernel(
    const float* __restrict__ partial, float* __restrict__ out) {
    const int t = threadIdx.x;
    float s = 0.0f;
#pragma unroll
    for (int i = 0; i < NBLK / 64; ++i) s += partial[t + i * 64];
#pragma unroll
    for (int o = 1; o <= 32; o <<= 1) s += __shfl_xor(s, o);
    if (t == 0) out[0] = s;
}

extern "C" void kernel_launch(void* const* d_in, const int* in_sizes, int n_in,
                              void* d_out, int out_size, void* d_ws, size_t ws_size,
                              hipStream_t stream) {
    const float* pred0 = (const float*)d_in[0];
    const float* pred1 = (const float*)d_in[1];
    const float* pred2 = (const float*)d_in[2];
    const float* gt    = (const float*)d_in[3];
    float* partial = (float*)d_ws;
    float* out     = (float*)d_out;

    chamfer_partial_kernel<<<NBLK, 256, 0, stream>>>(pred0, pred1, pred2, gt, partial);
    reduce_partials_kernel<<<1, 64, 0, stream>>>(partial, out);
}